// Round 12
// baseline (148.402 us; speedup 1.0000x reference)
//
#include <hip/hip_runtime.h>

#define Bb 2
#define Cc 512
#define Nn 2048
#define Mm 2048
#define Hh 8
#define HD 64
// exp(S*0.125) = 2^(S * 0.125*log2(e)); folded into Q at projection time
#define QSCALE 0.18033688011112042f

typedef unsigned short u16;
typedef unsigned int u32;
typedef __bf16 bf16x8 __attribute__((ext_vector_type(8)));
typedef float f32x16 __attribute__((ext_vector_type(16)));

union V4 {
    uint4 u;
    bf16x8 b;
};

__device__ __forceinline__ u16 f2bfu(float f) {
    unsigned int b = __float_as_uint(f);
    unsigned int r = (b + 0x7fffu + ((b >> 16) & 1u)) >> 16;
    return (u16)r;
}
__device__ __forceinline__ float bfu2f(u16 u) {
    return __uint_as_float(((unsigned int)u) << 16);
}
// pack two fp32 -> two bf16 (round-half-up) in one v_perm
__device__ __forceinline__ u32 pkbf(float lo, float hi_) {
    return __builtin_amdgcn_perm(__float_as_uint(hi_) + 0x8000u,
                                 __float_as_uint(lo) + 0x8000u, 0x07060302u);
}

// ---------------- one dispatch: all transposes + fp32->bf16 casts ------------------------
__global__ __launch_bounds__(256) void transpose_all(
    const float* __restrict__ x, const float* __restrict__ y, const float* __restrict__ Wq,
    const float* __restrict__ Wkv, const float* __restrict__ Wp, u16* __restrict__ xT,
    u16* __restrict__ yT, u16* __restrict__ WqT, u16* __restrict__ WkvT,
    u16* __restrict__ WpT) {
    __shared__ float tile[32][33];
    const int z = blockIdx.z;
    const float* in;
    u16* out;
    int S, sx = blockIdx.x;
    size_t base = 0;
    const int R = 512;
    if (z < 4) {
        in = (z < 2) ? x : y;
        out = (z < 2) ? xT : yT;
        S = 2048;
        base = (size_t)(z & 1) * R * S;
    } else {
        if (sx < 16) {
            in = Wq; out = WqT; S = 512;
        } else if (sx < 48) {
            in = Wkv; out = WkvT; S = 1024; sx -= 16;
        } else {
            in = Wp; out = WpT; S = 512; sx -= 48;
        }
    }
    int r0 = blockIdx.y * 32, s0 = sx * 32;
    int tx = threadIdx.x, ty = threadIdx.y;
#pragma unroll
    for (int k = 0; k < 4; k++)
        tile[ty + 8 * k][tx] = in[base + (size_t)(r0 + ty + 8 * k) * S + s0 + tx];
    __syncthreads();
#pragma unroll
    for (int k = 0; k < 4; k++)
        out[base + (size_t)(s0 + ty + 8 * k) * R + r0 + tx] = f2bfu(tile[tx][ty + 8 * k]);
}

// ---------------- fused projections: Q (scaled) + KV (split + conv fold) -----------------
__global__ __launch_bounds__(256) void proj_qkv(const u16* __restrict__ xT,
                                                const u16* __restrict__ yT,
                                                const u16* __restrict__ WqT,
                                                const u16* __restrict__ WkvT,
                                                const float* __restrict__ lw,
                                                const float* __restrict__ lb,
                                                u16* __restrict__ qb, u16* __restrict__ kb,
                                                u16* __restrict__ vtb) {
    __shared__ alignas(16) u16 As[2][128 * 64];
    __shared__ alignas(16) u16 Bs[2][64 * 64];
    const int t = threadIdx.x;
    const int lane = t & 63, w = t >> 6;
    const int r = lane & 31, hi = lane >> 5;
    const bool isQ = (blockIdx.x < 8);
    const int c0 = (isQ ? blockIdx.x : blockIdx.x - 8) * 64;
    const int r0 = blockIdx.y * 128;
    const int wr = (w & 1) * 64, wc = (w >> 1) * 32;
    const u16* A = isQ ? xT : yT;
    const u16* Bt = isQ ? WqT : WkvT;

    const int sra = t >> 3, ska = t & 7;
    const int swa = ((ska ^ (sra & 7)) << 3);
    const u16* Ag = A + (size_t)(r0 + sra) * 512 + ska * 8;
    const u16* Bg = Bt + (size_t)(c0 + sra) * 512 + ska * 8;

    {
#pragma unroll
        for (int i = 0; i < 4; i++)
            *(uint4*)&As[0][(sra + 32 * i) * 64 + swa] = *(const uint4*)(Ag + (size_t)i * 32 * 512);
#pragma unroll
        for (int i = 0; i < 2; i++)
            *(uint4*)&Bs[0][(sra + 32 * i) * 64 + swa] = *(const uint4*)(Bg + (size_t)i * 32 * 512);
    }
    __syncthreads();

    f32x16 acc[2];
#pragma unroll
    for (int rs = 0; rs < 2; rs++)
#pragma unroll
        for (int e = 0; e < 16; e++) acc[rs][e] = 0.f;

    const int ra0 = wr + r, ra1 = wr + 32 + r, rb = wc + r;

    for (int kk = 0; kk < 8; kk++) {
        const int cur = kk & 1;
        uint4 pa[4], pb[2];
        const bool more = (kk < 7);
        if (more) {
            const size_t ko = (size_t)(kk + 1) * 64;
#pragma unroll
            for (int i = 0; i < 4; i++) pa[i] = *(const uint4*)(Ag + (size_t)i * 32 * 512 + ko);
#pragma unroll
            for (int i = 0; i < 2; i++) pb[i] = *(const uint4*)(Bg + (size_t)i * 32 * 512 + ko);
        }
        V4 af[2][4], bf[4];
#pragma unroll
        for (int ks = 0; ks < 4; ks++) {
            const int c = 2 * ks + hi;
            bf[ks].u = *(const uint4*)&Bs[cur][rb * 64 + ((c ^ (rb & 7)) << 3)];
            af[0][ks].u = *(const uint4*)&As[cur][ra0 * 64 + ((c ^ (ra0 & 7)) << 3)];
            af[1][ks].u = *(const uint4*)&As[cur][ra1 * 64 + ((c ^ (ra1 & 7)) << 3)];
        }
#pragma unroll
        for (int ks = 0; ks < 4; ks++) {
            acc[0] = __builtin_amdgcn_mfma_f32_32x32x16_bf16(af[0][ks].b, bf[ks].b, acc[0], 0, 0, 0);
            acc[1] = __builtin_amdgcn_mfma_f32_32x32x16_bf16(af[1][ks].b, bf[ks].b, acc[1], 0, 0, 0);
        }
        if (more) {
            const int nxt = cur ^ 1;
#pragma unroll
            for (int i = 0; i < 4; i++) *(uint4*)&As[nxt][(sra + 32 * i) * 64 + swa] = pa[i];
#pragma unroll
            for (int i = 0; i < 2; i++) *(uint4*)&Bs[nxt][(sra + 32 * i) * 64 + swa] = pb[i];
        }
        __syncthreads();
    }

    const int cg = c0 + wc + r;
    if (isQ) {
#pragma unroll
        for (int rs = 0; rs < 2; rs++)
#pragma unroll
            for (int e = 0; e < 16; e++) {
                int m = r0 + wr + rs * 32 + 4 * hi + (e & 3) + 8 * (e >> 2);
                qb[(size_t)m * 512 + cg] = f2bfu(acc[rs][e] * QSCALE);
            }
    } else {
        const int hd = cg >> 1, s = cg & 1, h = hd >> 6, d = hd & 63;
        const int bq = r0 >> 11;
        const int bh = bq * 8 + h;
        const int mb = (r0 & 2047) + wr + 4 * hi;
        if (s == 0) {
            u16* kbase = kb + ((size_t)bh * 2048) * 64 + d;
#pragma unroll
            for (int rs = 0; rs < 2; rs++)
#pragma unroll
                for (int e = 0; e < 16; e++) {
                    int m = mb + rs * 32 + (e & 3) + 8 * (e >> 2);
                    kbase[(size_t)m * 64] = f2bfu(acc[rs][e]);
                }
        } else {
            const float sw = 1.0f + lw[hd], sb = lb[hd];
            u16* vbase = vtb + ((size_t)bh * 64 + d) * 2048;
#pragma unroll
            for (int rs = 0; rs < 2; rs++)
#pragma unroll
                for (int eg = 0; eg < 4; eg++) {
                    int m = mb + rs * 32 + 8 * eg;
                    float v0 = acc[rs][4 * eg + 0] * sw + sb;
                    float v1 = acc[rs][4 * eg + 1] * sw + sb;
                    float v2 = acc[rs][4 * eg + 2] * sw + sb;
                    float v3 = acc[rs][4 * eg + 3] * sw + sb;
                    uint2 pk;
                    pk.x = pkbf(v0, v1);
                    pk.y = pkbf(v2, v3);
                    *(uint2*)(vbase + m) = pk;
                }
        }
    }
}

// ---------------- flash attention v10: v9 epilogue + 8-way m-split, 3 blocks/CU ----------
// r10's occupancy experiment rerun without its write-amplification confound: sp=8 (4 m-
// iters/block), grid 1024, launch_bounds(256,3). Clean [n][d] po via LDS-staged epilogue.
__global__ __launch_bounds__(256, 3) void flash_attn(const u16* __restrict__ q,
                                                     const u16* __restrict__ kk,
                                                     const u16* __restrict__ vt,
                                                     u16* __restrict__ po,
                                                     float* __restrict__ ls) {
    __shared__ alignas(16) u16 SM[16384];  // Ks[2][4096] | Vs[2][4096]; reused for epilogue
    const int t = threadIdx.x;
    const int lane = t & 63, w = t >> 6;
    const int r = lane & 31, hi = lane >> 5;
    // XCD-locality decode: 128 (bh,sp) combos x 8 nt; combo pinned to xcd = id & 7
    const int id = blockIdx.x;
    const int xcd = id & 7, sid = id >> 3;
    const int combo = xcd * 16 + (sid >> 3);
    const int nt = sid & 7;
    const int bh = combo >> 3, sp = combo & 7;
    const int b = bh >> 3, h = bh & 7;
    const int nw0 = nt * 256 + 64 * w + r;  // n-half 0; n-half 1 = nw0 + 32
    const int MT0 = sp * 4, MT1 = MT0 + 4;

    // Q B-frags for both n-halves, loop-invariant (q pre-scaled by QSCALE)
    V4 qf[2][4];
    {
        const u16* qrow = q + ((size_t)(b * Nn + nw0)) * Cc + h * HD + hi * 8;
#pragma unroll
        for (int ks = 0; ks < 4; ks++) {
            qf[0][ks].u = *(const uint4*)(qrow + ks * 16);
            qf[1][ks].u = *(const uint4*)(qrow + 32 * Cc + ks * 16);
        }
    }

    const u16* kbase = kk + ((size_t)bh) * Mm * HD;
    const u16* vbase = vt + ((size_t)bh) * HD * Mm;

    const int cr0 = t >> 3, cc0 = t & 7;
    const int cr1 = cr0 + 32, cc1 = cc0;
    const int swa0 = cr0 * 64 + ((cc0 ^ (cr0 & 7)) << 3);
    const int swa1 = cr1 * 64 + ((cc1 ^ (cr1 & 7)) << 3);

    {
        int m00 = MT0 * 64;
        uint4 a0 = *(const uint4*)(kbase + (size_t)(m00 + cr0) * HD + cc0 * 8);
        uint4 a1 = *(const uint4*)(kbase + (size_t)(m00 + cr1) * HD + cc1 * 8);
        uint4 b0 = *(const uint4*)(vbase + (size_t)cr0 * Mm + m00 + cc0 * 8);
        uint4 b1 = *(const uint4*)(vbase + (size_t)cr1 * Mm + m00 + cc1 * 8);
        *(uint4*)&SM[swa0] = a0;
        *(uint4*)&SM[swa1] = a1;
        *(uint4*)&SM[8192 + swa0] = b0;
        *(uint4*)&SM[8192 + swa1] = b1;
    }
    __syncthreads();

    f32x16 oa[2][2];  // [v-half d32][n-half]
#pragma unroll
    for (int v = 0; v < 2; v++)
#pragma unroll
        for (int nh = 0; nh < 2; nh++)
#pragma unroll
            for (int e = 0; e < 16; e++) oa[v][nh][e] = 0.f;
    float lsum0 = 0.f, lsum1 = 0.f;

    for (int mt = MT0; mt < MT1; mt++) {
        const u16* Ksc = &SM[(mt & 1) * 4096];
        const u16* Vsc = &SM[8192 + (mt & 1) * 4096];
        uint4 nk0, nk1, nv0, nv1;
        const bool more = (mt + 1 < MT1);
        if (more) {
            int m0 = (mt + 1) * 64;
            nk0 = *(const uint4*)(kbase + (size_t)(m0 + cr0) * HD + cc0 * 8);
            nk1 = *(const uint4*)(kbase + (size_t)(m0 + cr1) * HD + cc1 * 8);
            nv0 = *(const uint4*)(vbase + (size_t)cr0 * Mm + m0 + cc0 * 8);
            nv1 = *(const uint4*)(vbase + (size_t)cr1 * Mm + m0 + cc1 * 8);
        }
        // fused per-32m-subtile pipeline: QK -> exp/pack -> PV
#pragma unroll
        for (int s = 0; s < 2; s++) {
            f32x16 sa0, sa1;
#pragma unroll
            for (int e = 0; e < 16; e++) {
                sa0[e] = 0.f;
                sa1[e] = 0.f;
            }
#pragma unroll
            for (int ks = 0; ks < 4; ks++) {
                V4 af;
                af.u = *(const uint4*)&Ksc[(32 * s + r) * 64 +
                                           (((2 * ks + hi) ^ (r & 7)) << 3)];
                sa0 = __builtin_amdgcn_mfma_f32_32x32x16_bf16(af.b, qf[0][ks].b, sa0, 0, 0, 0);
                sa1 = __builtin_amdgcn_mfma_f32_32x32x16_bf16(af.b, qf[1][ks].b, sa1, 0, 0, 0);
            }
            u32 p[2][8];
#pragma unroll
            for (int qq = 0; qq < 8; qq++) {
                float e0 = __builtin_amdgcn_exp2f(sa0[2 * qq]);
                float e1 = __builtin_amdgcn_exp2f(sa0[2 * qq + 1]);
                lsum0 += e0 + e1;
                p[0][qq] = pkbf(e0, e1);
                float f0 = __builtin_amdgcn_exp2f(sa1[2 * qq]);
                float f1 = __builtin_amdgcn_exp2f(sa1[2 * qq + 1]);
                lsum1 += f0 + f1;
                p[1][qq] = pkbf(f0, f1);
            }
            u32 xr[2][4];
#pragma unroll
            for (int nh = 0; nh < 2; nh++) {
                xr[nh][0] = __shfl_xor(hi ? p[nh][0] : p[nh][2], 32);
                xr[nh][1] = __shfl_xor(hi ? p[nh][1] : p[nh][3], 32);
                xr[nh][2] = __shfl_xor(hi ? p[nh][4] : p[nh][6], 32);
                xr[nh][3] = __shfl_xor(hi ? p[nh][5] : p[nh][7], 32);
            }
#pragma unroll
            for (int kl = 0; kl < 2; kl++) {
                V4 pf[2];
#pragma unroll
                for (int nh = 0; nh < 2; nh++) {
                    if (kl == 0) {
                        pf[nh].u.x = hi ? xr[nh][0] : p[nh][0];
                        pf[nh].u.y = hi ? xr[nh][1] : p[nh][1];
                        pf[nh].u.z = hi ? p[nh][2] : xr[nh][0];
                        pf[nh].u.w = hi ? p[nh][3] : xr[nh][1];
                    } else {
                        pf[nh].u.x = hi ? xr[nh][2] : p[nh][4];
                        pf[nh].u.y = hi ? xr[nh][3] : p[nh][5];
                        pf[nh].u.z = hi ? p[nh][6] : xr[nh][2];
                        pf[nh].u.w = hi ? p[nh][7] : xr[nh][3];
                    }
                }
                const int c = 4 * s + 2 * kl + hi;
                V4 vf0, vf1;
                vf0.u = *(const uint4*)&Vsc[r * 64 + ((c ^ (r & 7)) << 3)];
                vf1.u = *(const uint4*)&Vsc[(32 + r) * 64 + ((c ^ (r & 7)) << 3)];
                oa[0][0] = __builtin_amdgcn_mfma_f32_32x32x16_bf16(vf0.b, pf[0].b, oa[0][0], 0, 0, 0);
                oa[0][1] = __builtin_amdgcn_mfma_f32_32x32x16_bf16(vf0.b, pf[1].b, oa[0][1], 0, 0, 0);
                oa[1][0] = __builtin_amdgcn_mfma_f32_32x32x16_bf16(vf1.b, pf[0].b, oa[1][0], 0, 0, 0);
                oa[1][1] = __builtin_amdgcn_mfma_f32_32x32x16_bf16(vf1.b, pf[1].b, oa[1][1], 0, 0, 0);
            }
        }
        if (more) {
            const int nxt = (mt & 1) ^ 1;
            *(uint4*)&SM[nxt * 4096 + swa0] = nk0;
            *(uint4*)&SM[nxt * 4096 + swa1] = nk1;
            *(uint4*)&SM[8192 + nxt * 4096 + swa0] = nv0;
            *(uint4*)&SM[8192 + nxt * 4096 + swa1] = nv1;
        }
        __syncthreads();
    }

    lsum0 += __shfl_xor(lsum0, 32);
    lsum1 += __shfl_xor(lsum1, 32);

    // ---- epilogue: stage O-tile [n 64][d 64] in wave-private LDS, coalesced stores ----
    u16* stg = &SM[w * 4096];
#pragma unroll
    for (int v = 0; v < 2; v++)
#pragma unroll
        for (int nh = 0; nh < 2; nh++)
#pragma unroll
            for (int g = 0; g < 4; g++) {
                uint2 pk;
                pk.x = pkbf(oa[v][nh][4 * g + 0], oa[v][nh][4 * g + 1]);
                pk.y = pkbf(oa[v][nh][4 * g + 2], oa[v][nh][4 * g + 3]);
                const int row = r + 32 * nh;
                const int c8 = g + 4 * v;  // 16B chunk index along d
                *(uint2*)&stg[row * 64 + ((c8 ^ (row & 7)) << 3) + 4 * hi] = pk;
            }
    __syncthreads();
    const int W0 = nt * 256 + 64 * w;
    u16* pob = po + (((size_t)sp * 16 + bh) * 2048 + W0) * 64;
#pragma unroll
    for (int pp = 0; pp < 8; pp++) {
        const int nl = pp * 8 + (lane >> 3);
        const int cc = lane & 7;
        uint4 vv = *(const uint4*)&stg[nl * 64 + ((cc ^ (nl & 7)) << 3)];
        *(uint4*)&pob[(size_t)nl * 64 + cc * 8] = vv;
    }
    if (hi == 0) {
        ls[((size_t)sp * 16 + bh) * 2048 + nw0] = lsum0;
        ls[((size_t)sp * 16 + bh) * 2048 + nw0 + 32] = lsum1;
    }
}

// ---------------- combine 8 m-split bf16 partials (po [sp][bh][n][d]) -> bf16 O ----------
__global__ __launch_bounds__(256) void combine_o(const u16* __restrict__ po,
                                                 const float* __restrict__ ls,
                                                 u16* __restrict__ o) {
    const int t = threadIdx.x;
    const int n0 = blockIdx.x * 64, bh = blockIdx.y;
    const int nn = t >> 2, dq = (t & 3) * 16;
    const int n = n0 + nn;
    float s = 0.f;
#pragma unroll
    for (int sp = 0; sp < 8; sp++) s += ls[((size_t)sp * 16 + bh) * 2048 + n];
    const float linv = 1.0f / s;
    float acc[16];
#pragma unroll
    for (int i = 0; i < 16; i++) acc[i] = 0.f;
#pragma unroll
    for (int sp = 0; sp < 8; sp++) {
        const u16* pr = po + (((size_t)sp * 16 + bh) * 2048 + n) * 64 + dq;
        uint4 a = *(const uint4*)pr;
        uint4 b = *(const uint4*)(pr + 8);
        const u16* pa = (const u16*)&a;
        const u16* pb = (const u16*)&b;
#pragma unroll
        for (int i = 0; i < 8; i++) {
            acc[i] += bfu2f(pa[i]);
            acc[8 + i] += bfu2f(pb[i]);
        }
    }
    const int b_ = bh >> 3, h = bh & 7;
    u16* orow = o + ((size_t)(b_ * Nn + n)) * Cc + h * 64 + dq;
    uint4 o0, o1;
    u32* q0 = (u32*)&o0;
    u32* q1 = (u32*)&o1;
#pragma unroll
    for (int i = 0; i < 4; i++) {
        q0[i] = pkbf(acc[2 * i] * linv, acc[2 * i + 1] * linv);
        q1[i] = pkbf(acc[8 + 2 * i] * linv, acc[8 + 2 * i + 1] * linv);
    }
    *(uint4*)orow = o0;
    *(uint4*)(orow + 8) = o1;
}

// ---------------- final GEMM: out^T[c][bn] = sum_k Wp[k][c]*ob[bn][k] + bias[c] ----------
__global__ __launch_bounds__(256) void gemm_out(const u16* __restrict__ Wt,
                                                const u16* __restrict__ Ob,
                                                float* __restrict__ out,
                                                const float* __restrict__ bias) {
    __shared__ alignas(16) u16 Ws[2][64 * 64];
    __shared__ alignas(16) u16 Os[2][128 * 64];
    const int t = threadIdx.x;
    const int lane = t & 63, w = t >> 6;
    const int r = lane & 31, hi = lane >> 5;
    const int c0 = blockIdx.x * 64, n0 = blockIdx.y * 128;
    const int cb = (w & 1) * 32, nb = (w >> 1) * 32;

    const int sra = t >> 3, ska = t & 7;
    const int swa = ((ska ^ (sra & 7)) << 3);
    const u16* Wg = Wt + (size_t)(c0 + sra) * 512 + ska * 8;
    const u16* Og = Ob + (size_t)(n0 + sra) * 512 + ska * 8;

    {
#pragma unroll
        for (int i = 0; i < 2; i++)
            *(uint4*)&Ws[0][(sra + 32 * i) * 64 + swa] = *(const uint4*)(Wg + (size_t)i * 32 * 512);
#pragma unroll
        for (int i = 0; i < 4; i++)
            *(uint4*)&Os[0][(sra + 32 * i) * 64 + swa] = *(const uint4*)(Og + (size_t)i * 32 * 512);
    }
    __syncthreads();

    f32x16 acc[2];
#pragma unroll
    for (int ns = 0; ns < 2; ns++)
#pragma unroll
        for (int e = 0; e < 16; e++) acc[ns][e] = 0.f;

    const int rw = cb + r, ro0 = nb + r, ro1 = nb + 64 + r;

    for (int kk = 0; kk < 8; kk++) {
        const int cur = kk & 1;
        uint4 pw[2], po_[4];
        const bool more = (kk < 7);
        if (more) {
            const size_t ko = (size_t)(kk + 1) * 64;
#pragma unroll
            for (int i = 0; i < 2; i++) pw[i] = *(const uint4*)(Wg + (size_t)i * 32 * 512 + ko);
#pragma unroll
            for (int i = 0; i < 4; i++) po_[i] = *(const uint4*)(Og + (size_t)i * 32 * 512 + ko);
        }
        V4 wf[4], of[2][4];
#pragma unroll
        for (int ks = 0; ks < 4; ks++) {
            const int c = 2 * ks + hi;
            wf[ks].u = *(const uint4*)&Ws[cur][rw * 64 + ((c ^ (rw & 7)) << 3)];
            of[0][ks].u = *(const uint4*)&Os[cur][ro0 * 64 + ((c ^ (ro0 & 7)) << 3)];
            of[1][ks].u = *(const uint4*)&Os[cur][ro1 * 64 + ((c ^ (ro1 & 7)) << 3)];
        }
#pragma unroll
        for (int ks = 0; ks < 4; ks++) {
            acc[0] = __builtin_amdgcn_mfma_f32_32x32x16_bf16(wf[ks].b, of[0][ks].b, acc[0], 0, 0, 0);
            acc[1] = __builtin_amdgcn_mfma_f32_32x32x16_bf16(wf[ks].b, of[1][ks].b, acc[1], 0, 0, 0);
        }
        if (more) {
            const int nxt = cur ^ 1;
#pragma unroll
            for (int i = 0; i < 2; i++) *(uint4*)&Ws[nxt][(sra + 32 * i) * 64 + swa] = pw[i];
#pragma unroll
            for (int i = 0; i < 4; i++) *(uint4*)&Os[nxt][(sra + 32 * i) * 64 + swa] = po_[i];
        }
        __syncthreads();
    }

#pragma unroll
    for (int e = 0; e < 16; e++) {
        const int c_r = c0 + cb + 4 * hi + (e & 3) + 8 * (e >> 2);
        const float bv = bias[c_r];
#pragma unroll
        for (int ns = 0; ns < 2; ns++) {
            const int rg = n0 + nb + ns * 64 + r;
            const int b = rg >> 11, n = rg & 2047;
            out[((size_t)b * 512 + c_r) * 2048 + n] = acc[ns][e] + bv;
        }
    }
}

// ---------------- workspace layout (bytes) ----------------
static const size_t OFF_XT = 0;
static const size_t OFF_YT = 4194304;
static const size_t OFF_WQT = 8388608;
static const size_t OFF_WKVT = 8912896;
static const size_t OFF_WPT = 9961472;
static const size_t OFF_Q = 10485760;
static const size_t OFF_K = 23068672;
static const size_t OFF_VT = 27262976;
static const size_t OFF_O = 31457280;
static const size_t OFF_PO = 35651584;  // 32 MB bf16 partial O [8][16][2048 n][64 d]
static const size_t OFF_LS = 69206016;  // fp32 partial lsum [8][16][2048]

extern "C" void kernel_launch(void* const* d_in, const int* in_sizes, int n_in,
                              void* d_out, int out_size, void* d_ws, size_t ws_size,
                              hipStream_t stream) {
    const float* x = (const float*)d_in[0];
    const float* y = (const float*)d_in[1];
    const float* Wq = (const float*)d_in[2];
    const float* Wkv = (const float*)d_in[3];
    const float* lw = (const float*)d_in[4];
    const float* lb = (const float*)d_in[5];
    const float* Wp = (const float*)d_in[6];
    const float* bp = (const float*)d_in[7];

    char* ws = (char*)d_ws;
    u16* xT = (u16*)(ws + OFF_XT);
    u16* yT = (u16*)(ws + OFF_YT);
    u16* WqT = (u16*)(ws + OFF_WQT);
    u16* WkvT = (u16*)(ws + OFF_WKVT);
    u16* WpT = (u16*)(ws + OFF_WPT);
    u16* qb = (u16*)(ws + OFF_Q);
    u16* kb = (u16*)(ws + OFF_K);
    u16* vtb = (u16*)(ws + OFF_VT);
    u16* ob = (u16*)(ws + OFF_O);
    u16* po = (u16*)(ws + OFF_PO);
    float* lsw = (float*)(ws + OFF_LS);

    dim3 tb(32, 8, 1);
    transpose_all<<<dim3(64, 16, 5), tb, 0, stream>>>(x, y, Wq, Wkv, Wp, xT, yT, WqT, WkvT,
                                                      WpT);
    proj_qkv<<<dim3(24, 32), 256, 0, stream>>>(xT, yT, WqT, WkvT, lw, lb, qb, kb, vtb);
    flash_attn<<<dim3(1024), 256, 0, stream>>>(qb, kb, vtb, po, lsw);
    combine_o<<<dim3(32, 16), 256, 0, stream>>>(po, lsw, ob);
    gemm_out<<<dim3(8, 32), 256, 0, stream>>>(WpT, ob, (float*)d_out, bp);
}

// Round 13
// 132.915 us; speedup vs baseline: 1.1165x; 1.1165x over previous
//
#include <hip/hip_runtime.h>

#define Bb 2
#define Cc 512
#define Nn 2048
#define Mm 2048
#define Hh 8
#define HD 64
// exp(S*0.125) = 2^(S * 0.125*log2(e)); folded into Q at projection time
#define QSCALE 0.18033688011112042f

typedef unsigned short u16;
typedef unsigned int u32;
typedef __bf16 bf16x8 __attribute__((ext_vector_type(8)));
typedef float f32x16 __attribute__((ext_vector_type(16)));

union V4 {
    uint4 u;
    bf16x8 b;
};

__device__ __forceinline__ u16 f2bfu(float f) {
    unsigned int b = __float_as_uint(f);
    unsigned int r = (b + 0x7fffu + ((b >> 16) & 1u)) >> 16;
    return (u16)r;
}
__device__ __forceinline__ float bfu2f(u16 u) {
    return __uint_as_float(((unsigned int)u) << 16);
}
// pack two fp32 -> two bf16 (round-half-up) in one v_perm
__device__ __forceinline__ u32 pkbf(float lo, float hi_) {
    return __builtin_amdgcn_perm(__float_as_uint(hi_) + 0x8000u,
                                 __float_as_uint(lo) + 0x8000u, 0x07060302u);
}

// ---------------- one dispatch: all transposes + fp32->bf16 casts ------------------------
__global__ __launch_bounds__(256) void transpose_all(
    const float* __restrict__ x, const float* __restrict__ y, const float* __restrict__ Wq,
    const float* __restrict__ Wkv, const float* __restrict__ Wp, u16* __restrict__ xT,
    u16* __restrict__ yT, u16* __restrict__ WqT, u16* __restrict__ WkvT,
    u16* __restrict__ WpT) {
    __shared__ float tile[32][33];
    const int z = blockIdx.z;
    const float* in;
    u16* out;
    int S, sx = blockIdx.x;
    size_t base = 0;
    const int R = 512;
    if (z < 4) {
        in = (z < 2) ? x : y;
        out = (z < 2) ? xT : yT;
        S = 2048;
        base = (size_t)(z & 1) * R * S;
    } else {
        if (sx < 16) {
            in = Wq; out = WqT; S = 512;
        } else if (sx < 48) {
            in = Wkv; out = WkvT; S = 1024; sx -= 16;
        } else {
            in = Wp; out = WpT; S = 512; sx -= 48;
        }
    }
    int r0 = blockIdx.y * 32, s0 = sx * 32;
    int tx = threadIdx.x, ty = threadIdx.y;
#pragma unroll
    for (int k = 0; k < 4; k++)
        tile[ty + 8 * k][tx] = in[base + (size_t)(r0 + ty + 8 * k) * S + s0 + tx];
    __syncthreads();
#pragma unroll
    for (int k = 0; k < 4; k++)
        out[base + (size_t)(s0 + ty + 8 * k) * R + r0 + tx] = f2bfu(tile[tx][ty + 8 * k]);
}

// ---------------- fused projections v2: 128x128 tile, 4 waves x (64x64), dbuf ------------
// blockIdx.x < 4: Q path (xT @ WqT); else KV path (yT @ WkvT) with split + conv fold.
__global__ __launch_bounds__(256, 2) void proj_qkv(const u16* __restrict__ xT,
                                                   const u16* __restrict__ yT,
                                                   const u16* __restrict__ WqT,
                                                   const u16* __restrict__ WkvT,
                                                   const float* __restrict__ lw,
                                                   const float* __restrict__ lb,
                                                   u16* __restrict__ qb,
                                                   u16* __restrict__ kb,
                                                   u16* __restrict__ vtb) {
    __shared__ alignas(16) u16 As[2][128 * 64];
    __shared__ alignas(16) u16 Bs[2][128 * 64];
    const int t = threadIdx.x;
    const int lane = t & 63, w = t >> 6;
    const int r = lane & 31, hi = lane >> 5;
    const bool isQ = (blockIdx.x < 4);
    const int c0 = (isQ ? blockIdx.x : blockIdx.x - 4) * 128;
    const int r0 = blockIdx.y * 128;
    const int wr = (w & 1) * 64, wc = (w >> 1) * 64;
    const u16* A = isQ ? xT : yT;
    const u16* Bt = isQ ? WqT : WkvT;

    const int sra = t >> 3, ska = t & 7;
    const int swa = ((ska ^ (sra & 7)) << 3);  // (row&7) invariant under +32
    const u16* Ag = A + (size_t)(r0 + sra) * 512 + ska * 8;
    const u16* Bg = Bt + (size_t)(c0 + sra) * 512 + ska * 8;

    {  // stage k-block 0
#pragma unroll
        for (int i = 0; i < 4; i++) {
            *(uint4*)&As[0][(sra + 32 * i) * 64 + swa] = *(const uint4*)(Ag + (size_t)i * 32 * 512);
            *(uint4*)&Bs[0][(sra + 32 * i) * 64 + swa] = *(const uint4*)(Bg + (size_t)i * 32 * 512);
        }
    }
    __syncthreads();

    f32x16 acc[2][2];
#pragma unroll
    for (int rs = 0; rs < 2; rs++)
#pragma unroll
        for (int cs = 0; cs < 2; cs++)
#pragma unroll
            for (int e = 0; e < 16; e++) acc[rs][cs][e] = 0.f;

    const int ra0 = wr + r, ra1 = wr + 32 + r;
    const int rb0 = wc + r, rb1 = wc + 32 + r;

    for (int kk = 0; kk < 8; kk++) {
        const int cur = kk & 1;
        uint4 pa[4], pb[4];
        const bool more = (kk < 7);
        if (more) {
            const size_t ko = (size_t)(kk + 1) * 64;
#pragma unroll
            for (int i = 0; i < 4; i++) {
                pa[i] = *(const uint4*)(Ag + (size_t)i * 32 * 512 + ko);
                pb[i] = *(const uint4*)(Bg + (size_t)i * 32 * 512 + ko);
            }
        }
#pragma unroll
        for (int ks = 0; ks < 4; ks++) {
            const int c = 2 * ks + hi;
            V4 af0, af1, bf0, bf1;
            af0.u = *(const uint4*)&As[cur][ra0 * 64 + ((c ^ (ra0 & 7)) << 3)];
            af1.u = *(const uint4*)&As[cur][ra1 * 64 + ((c ^ (ra1 & 7)) << 3)];
            bf0.u = *(const uint4*)&Bs[cur][rb0 * 64 + ((c ^ (rb0 & 7)) << 3)];
            bf1.u = *(const uint4*)&Bs[cur][rb1 * 64 + ((c ^ (rb1 & 7)) << 3)];
            acc[0][0] = __builtin_amdgcn_mfma_f32_32x32x16_bf16(af0.b, bf0.b, acc[0][0], 0, 0, 0);
            acc[0][1] = __builtin_amdgcn_mfma_f32_32x32x16_bf16(af0.b, bf1.b, acc[0][1], 0, 0, 0);
            acc[1][0] = __builtin_amdgcn_mfma_f32_32x32x16_bf16(af1.b, bf0.b, acc[1][0], 0, 0, 0);
            acc[1][1] = __builtin_amdgcn_mfma_f32_32x32x16_bf16(af1.b, bf1.b, acc[1][1], 0, 0, 0);
        }
        if (more) {
            const int nxt = cur ^ 1;
#pragma unroll
            for (int i = 0; i < 4; i++) {
                *(uint4*)&As[nxt][(sra + 32 * i) * 64 + swa] = pa[i];
                *(uint4*)&Bs[nxt][(sra + 32 * i) * 64 + swa] = pb[i];
            }
        }
        __syncthreads();
    }

    if (isQ) {
#pragma unroll
        for (int rs = 0; rs < 2; rs++)
#pragma unroll
            for (int cs = 0; cs < 2; cs++) {
                const int cg = c0 + wc + cs * 32 + r;
#pragma unroll
                for (int e = 0; e < 16; e++) {
                    int m = r0 + wr + rs * 32 + 4 * hi + (e & 3) + 8 * (e >> 2);
                    qb[(size_t)m * 512 + cg] = f2bfu(acc[rs][cs][e] * QSCALE);
                }
            }
    } else {
        const int bq = r0 >> 11;
        const int mb = (r0 & 2047) + wr + 4 * hi;
#pragma unroll
        for (int cs = 0; cs < 2; cs++) {
            const int cg = c0 + wc + cs * 32 + r;
            const int hd = cg >> 1, s = cg & 1, h = hd >> 6, d = hd & 63;
            const int bh = bq * 8 + h;
            if (s == 0) {
                u16* kbase = kb + ((size_t)bh * 2048) * 64 + d;
#pragma unroll
                for (int rs = 0; rs < 2; rs++)
#pragma unroll
                    for (int e = 0; e < 16; e++) {
                        int m = mb + rs * 32 + (e & 3) + 8 * (e >> 2);
                        kbase[(size_t)m * 64] = f2bfu(acc[rs][cs][e]);
                    }
            } else {
                const float sw = 1.0f + lw[hd], sb = lb[hd];
                u16* vbase = vtb + ((size_t)bh * 64 + d) * 2048;
#pragma unroll
                for (int rs = 0; rs < 2; rs++)
#pragma unroll
                    for (int eg = 0; eg < 4; eg++) {
                        int m = mb + rs * 32 + 8 * eg;
                        float v0 = acc[rs][cs][4 * eg + 0] * sw + sb;
                        float v1 = acc[rs][cs][4 * eg + 1] * sw + sb;
                        float v2 = acc[rs][cs][4 * eg + 2] * sw + sb;
                        float v3 = acc[rs][cs][4 * eg + 3] * sw + sb;
                        uint2 pk;
                        pk.x = pkbf(v0, v1);
                        pk.y = pkbf(v2, v3);
                        *(uint2*)(vbase + m) = pk;
                    }
            }
        }
    }
}

// ---------------- flash attention v9 (r11): sp=4, n64 reg-blocking, LDS-staged epilogue --
__global__ __launch_bounds__(256, 2) void flash_attn(const u16* __restrict__ q,
                                                     const u16* __restrict__ kk,
                                                     const u16* __restrict__ vt,
                                                     u16* __restrict__ po,
                                                     float* __restrict__ ls) {
    __shared__ alignas(16) u16 SM[16384];  // Ks[2][4096] | Vs[2][4096]; reused for epilogue
    const int t = threadIdx.x;
    const int lane = t & 63, w = t >> 6;
    const int r = lane & 31, hi = lane >> 5;
    // XCD-locality decode: 64 (bh,sp) combos x 8 nt; combo pinned to xcd = id & 7
    const int id = blockIdx.x;
    const int xcd = id & 7, sid = id >> 3;
    const int combo = xcd * 8 + (sid >> 3);
    const int nt = sid & 7;
    const int bh = combo >> 2, sp = combo & 3;
    const int b = bh >> 3, h = bh & 7;
    const int nw0 = nt * 256 + 64 * w + r;  // n-half 0; n-half 1 = nw0 + 32
    const int MT0 = sp * 8, MT1 = MT0 + 8;

    // Q B-frags for both n-halves, loop-invariant (q pre-scaled by QSCALE)
    V4 qf[2][4];
    {
        const u16* qrow = q + ((size_t)(b * Nn + nw0)) * Cc + h * HD + hi * 8;
#pragma unroll
        for (int ks = 0; ks < 4; ks++) {
            qf[0][ks].u = *(const uint4*)(qrow + ks * 16);
            qf[1][ks].u = *(const uint4*)(qrow + 32 * Cc + ks * 16);
        }
    }

    const u16* kbase = kk + ((size_t)bh) * Mm * HD;
    const u16* vbase = vt + ((size_t)bh) * HD * Mm;

    const int cr0 = t >> 3, cc0 = t & 7;
    const int cr1 = cr0 + 32, cc1 = cc0;
    const int swa0 = cr0 * 64 + ((cc0 ^ (cr0 & 7)) << 3);
    const int swa1 = cr1 * 64 + ((cc1 ^ (cr1 & 7)) << 3);

    {
        int m00 = MT0 * 64;
        uint4 a0 = *(const uint4*)(kbase + (size_t)(m00 + cr0) * HD + cc0 * 8);
        uint4 a1 = *(const uint4*)(kbase + (size_t)(m00 + cr1) * HD + cc1 * 8);
        uint4 b0 = *(const uint4*)(vbase + (size_t)cr0 * Mm + m00 + cc0 * 8);
        uint4 b1 = *(const uint4*)(vbase + (size_t)cr1 * Mm + m00 + cc1 * 8);
        *(uint4*)&SM[swa0] = a0;
        *(uint4*)&SM[swa1] = a1;
        *(uint4*)&SM[8192 + swa0] = b0;
        *(uint4*)&SM[8192 + swa1] = b1;
    }
    __syncthreads();

    f32x16 oa[2][2];  // [v-half d32][n-half]
#pragma unroll
    for (int v = 0; v < 2; v++)
#pragma unroll
        for (int nh = 0; nh < 2; nh++)
#pragma unroll
            for (int e = 0; e < 16; e++) oa[v][nh][e] = 0.f;
    float lsum0 = 0.f, lsum1 = 0.f;

    for (int mt = MT0; mt < MT1; mt++) {
        const u16* Ksc = &SM[(mt & 1) * 4096];
        const u16* Vsc = &SM[8192 + (mt & 1) * 4096];
        uint4 nk0, nk1, nv0, nv1;
        const bool more = (mt + 1 < MT1);
        if (more) {
            int m0 = (mt + 1) * 64;
            nk0 = *(const uint4*)(kbase + (size_t)(m0 + cr0) * HD + cc0 * 8);
            nk1 = *(const uint4*)(kbase + (size_t)(m0 + cr1) * HD + cc1 * 8);
            nv0 = *(const uint4*)(vbase + (size_t)cr0 * Mm + m0 + cc0 * 8);
            nv1 = *(const uint4*)(vbase + (size_t)cr1 * Mm + m0 + cc1 * 8);
        }
        // fused per-32m-subtile pipeline: QK -> exp/pack -> PV
#pragma unroll
        for (int s = 0; s < 2; s++) {
            f32x16 sa0, sa1;
#pragma unroll
            for (int e = 0; e < 16; e++) {
                sa0[e] = 0.f;
                sa1[e] = 0.f;
            }
#pragma unroll
            for (int ks = 0; ks < 4; ks++) {
                V4 af;
                af.u = *(const uint4*)&Ksc[(32 * s + r) * 64 +
                                           (((2 * ks + hi) ^ (r & 7)) << 3)];
                sa0 = __builtin_amdgcn_mfma_f32_32x32x16_bf16(af.b, qf[0][ks].b, sa0, 0, 0, 0);
                sa1 = __builtin_amdgcn_mfma_f32_32x32x16_bf16(af.b, qf[1][ks].b, sa1, 0, 0, 0);
            }
            u32 p[2][8];
#pragma unroll
            for (int qq = 0; qq < 8; qq++) {
                float e0 = __builtin_amdgcn_exp2f(sa0[2 * qq]);
                float e1 = __builtin_amdgcn_exp2f(sa0[2 * qq + 1]);
                lsum0 += e0 + e1;
                p[0][qq] = pkbf(e0, e1);
                float f0 = __builtin_amdgcn_exp2f(sa1[2 * qq]);
                float f1 = __builtin_amdgcn_exp2f(sa1[2 * qq + 1]);
                lsum1 += f0 + f1;
                p[1][qq] = pkbf(f0, f1);
            }
            u32 xr[2][4];
#pragma unroll
            for (int nh = 0; nh < 2; nh++) {
                xr[nh][0] = __shfl_xor(hi ? p[nh][0] : p[nh][2], 32);
                xr[nh][1] = __shfl_xor(hi ? p[nh][1] : p[nh][3], 32);
                xr[nh][2] = __shfl_xor(hi ? p[nh][4] : p[nh][6], 32);
                xr[nh][3] = __shfl_xor(hi ? p[nh][5] : p[nh][7], 32);
            }
#pragma unroll
            for (int kl = 0; kl < 2; kl++) {
                V4 pf[2];
#pragma unroll
                for (int nh = 0; nh < 2; nh++) {
                    if (kl == 0) {
                        pf[nh].u.x = hi ? xr[nh][0] : p[nh][0];
                        pf[nh].u.y = hi ? xr[nh][1] : p[nh][1];
                        pf[nh].u.z = hi ? p[nh][2] : xr[nh][0];
                        pf[nh].u.w = hi ? p[nh][3] : xr[nh][1];
                    } else {
                        pf[nh].u.x = hi ? xr[nh][2] : p[nh][4];
                        pf[nh].u.y = hi ? xr[nh][3] : p[nh][5];
                        pf[nh].u.z = hi ? p[nh][6] : xr[nh][2];
                        pf[nh].u.w = hi ? p[nh][7] : xr[nh][3];
                    }
                }
                const int c = 4 * s + 2 * kl + hi;
                V4 vf0, vf1;
                vf0.u = *(const uint4*)&Vsc[r * 64 + ((c ^ (r & 7)) << 3)];
                vf1.u = *(const uint4*)&Vsc[(32 + r) * 64 + ((c ^ (r & 7)) << 3)];
                oa[0][0] = __builtin_amdgcn_mfma_f32_32x32x16_bf16(vf0.b, pf[0].b, oa[0][0], 0, 0, 0);
                oa[0][1] = __builtin_amdgcn_mfma_f32_32x32x16_bf16(vf0.b, pf[1].b, oa[0][1], 0, 0, 0);
                oa[1][0] = __builtin_amdgcn_mfma_f32_32x32x16_bf16(vf1.b, pf[0].b, oa[1][0], 0, 0, 0);
                oa[1][1] = __builtin_amdgcn_mfma_f32_32x32x16_bf16(vf1.b, pf[1].b, oa[1][1], 0, 0, 0);
            }
        }
        if (more) {
            const int nxt = (mt & 1) ^ 1;
            *(uint4*)&SM[nxt * 4096 + swa0] = nk0;
            *(uint4*)&SM[nxt * 4096 + swa1] = nk1;
            *(uint4*)&SM[8192 + nxt * 4096 + swa0] = nv0;
            *(uint4*)&SM[8192 + nxt * 4096 + swa1] = nv1;
        }
        __syncthreads();
    }

    lsum0 += __shfl_xor(lsum0, 32);
    lsum1 += __shfl_xor(lsum1, 32);

    // ---- epilogue: stage O-tile [n 64][d 64] in wave-private LDS, coalesced stores ----
    u16* stg = &SM[w * 4096];
#pragma unroll
    for (int v = 0; v < 2; v++)
#pragma unroll
        for (int nh = 0; nh < 2; nh++)
#pragma unroll
            for (int g = 0; g < 4; g++) {
                uint2 pk;
                pk.x = pkbf(oa[v][nh][4 * g + 0], oa[v][nh][4 * g + 1]);
                pk.y = pkbf(oa[v][nh][4 * g + 2], oa[v][nh][4 * g + 3]);
                const int row = r + 32 * nh;
                const int c8 = g + 4 * v;  // 16B chunk index along d
                *(uint2*)&stg[row * 64 + ((c8 ^ (row & 7)) << 3) + 4 * hi] = pk;
            }
    __syncthreads();
    const int W0 = nt * 256 + 64 * w;
    u16* pob = po + (((size_t)sp * 16 + bh) * 2048 + W0) * 64;
#pragma unroll
    for (int pp = 0; pp < 8; pp++) {
        const int nl = pp * 8 + (lane >> 3);
        const int cc = lane & 7;
        uint4 vv = *(const uint4*)&stg[nl * 64 + ((cc ^ (nl & 7)) << 3)];
        *(uint4*)&pob[(size_t)nl * 64 + cc * 8] = vv;
    }
    if (hi == 0) {
        ls[((size_t)sp * 16 + bh) * 2048 + nw0] = lsum0;
        ls[((size_t)sp * 16 + bh) * 2048 + nw0 + 32] = lsum1;
    }
}

// ---------------- combine 4 m-split bf16 partials (po [sp][bh][n][d]) -> bf16 O ----------
__global__ __launch_bounds__(256) void combine_o(const u16* __restrict__ po,
                                                 const float* __restrict__ ls,
                                                 u16* __restrict__ o) {
    const int t = threadIdx.x;
    const int n0 = blockIdx.x * 64, bh = blockIdx.y;
    const int nn = t >> 2, dq = (t & 3) * 16;
    const int n = n0 + nn;
    float s = 0.f;
#pragma unroll
    for (int sp = 0; sp < 4; sp++) s += ls[((size_t)sp * 16 + bh) * 2048 + n];
    const float linv = 1.0f / s;
    float acc[16];
#pragma unroll
    for (int i = 0; i < 16; i++) acc[i] = 0.f;
#pragma unroll
    for (int sp = 0; sp < 4; sp++) {
        const u16* pr = po + (((size_t)sp * 16 + bh) * 2048 + n) * 64 + dq;
        uint4 a = *(const uint4*)pr;
        uint4 b = *(const uint4*)(pr + 8);
        const u16* pa = (const u16*)&a;
        const u16* pb = (const u16*)&b;
#pragma unroll
        for (int i = 0; i < 8; i++) {
            acc[i] += bfu2f(pa[i]);
            acc[8 + i] += bfu2f(pb[i]);
        }
    }
    const int b_ = bh >> 3, h = bh & 7;
    u16* orow = o + ((size_t)(b_ * Nn + n)) * Cc + h * 64 + dq;
    uint4 o0, o1;
    u32* q0 = (u32*)&o0;
    u32* q1 = (u32*)&o1;
#pragma unroll
    for (int i = 0; i < 4; i++) {
        q0[i] = pkbf(acc[2 * i] * linv, acc[2 * i + 1] * linv);
        q1[i] = pkbf(acc[8 + 2 * i] * linv, acc[8 + 2 * i + 1] * linv);
    }
    *(uint4*)orow = o0;
    *(uint4*)(orow + 8) = o1;
}

// ---------------- final GEMM: out^T[c][bn] = sum_k Wp[k][c]*ob[bn][k] + bias[c] ----------
__global__ __launch_bounds__(256) void gemm_out(const u16* __restrict__ Wt,
                                                const u16* __restrict__ Ob,
                                                float* __restrict__ out,
                                                const float* __restrict__ bias) {
    __shared__ alignas(16) u16 Ws[2][64 * 64];
    __shared__ alignas(16) u16 Os[2][128 * 64];
    const int t = threadIdx.x;
    const int lane = t & 63, w = t >> 6;
    const int r = lane & 31, hi = lane >> 5;
    const int c0 = blockIdx.x * 64, n0 = blockIdx.y * 128;
    const int cb = (w & 1) * 32, nb = (w >> 1) * 32;

    const int sra = t >> 3, ska = t & 7;
    const int swa = ((ska ^ (sra & 7)) << 3);
    const u16* Wg = Wt + (size_t)(c0 + sra) * 512 + ska * 8;
    const u16* Og = Ob + (size_t)(n0 + sra) * 512 + ska * 8;

    {
#pragma unroll
        for (int i = 0; i < 2; i++)
            *(uint4*)&Ws[0][(sra + 32 * i) * 64 + swa] = *(const uint4*)(Wg + (size_t)i * 32 * 512);
#pragma unroll
        for (int i = 0; i < 4; i++)
            *(uint4*)&Os[0][(sra + 32 * i) * 64 + swa] = *(const uint4*)(Og + (size_t)i * 32 * 512);
    }
    __syncthreads();

    f32x16 acc[2];
#pragma unroll
    for (int ns = 0; ns < 2; ns++)
#pragma unroll
        for (int e = 0; e < 16; e++) acc[ns][e] = 0.f;

    const int rw = cb + r, ro0 = nb + r, ro1 = nb + 64 + r;

    for (int kk = 0; kk < 8; kk++) {
        const int cur = kk & 1;
        uint4 pw[2], po_[4];
        const bool more = (kk < 7);
        if (more) {
            const size_t ko = (size_t)(kk + 1) * 64;
#pragma unroll
            for (int i = 0; i < 2; i++) pw[i] = *(const uint4*)(Wg + (size_t)i * 32 * 512 + ko);
#pragma unroll
            for (int i = 0; i < 4; i++) po_[i] = *(const uint4*)(Og + (size_t)i * 32 * 512 + ko);
        }
        V4 wf[4], of[2][4];
#pragma unroll
        for (int ks = 0; ks < 4; ks++) {
            const int c = 2 * ks + hi;
            wf[ks].u = *(const uint4*)&Ws[cur][rw * 64 + ((c ^ (rw & 7)) << 3)];
            of[0][ks].u = *(const uint4*)&Os[cur][ro0 * 64 + ((c ^ (ro0 & 7)) << 3)];
            of[1][ks].u = *(const uint4*)&Os[cur][ro1 * 64 + ((c ^ (ro1 & 7)) << 3)];
        }
#pragma unroll
        for (int ks = 0; ks < 4; ks++) {
            acc[0] = __builtin_amdgcn_mfma_f32_32x32x16_bf16(wf[ks].b, of[0][ks].b, acc[0], 0, 0, 0);
            acc[1] = __builtin_amdgcn_mfma_f32_32x32x16_bf16(wf[ks].b, of[1][ks].b, acc[1], 0, 0, 0);
        }
        if (more) {
            const int nxt = cur ^ 1;
#pragma unroll
            for (int i = 0; i < 2; i++) *(uint4*)&Ws[nxt][(sra + 32 * i) * 64 + swa] = pw[i];
#pragma unroll
            for (int i = 0; i < 4; i++) *(uint4*)&Os[nxt][(sra + 32 * i) * 64 + swa] = po_[i];
        }
        __syncthreads();
    }

#pragma unroll
    for (int e = 0; e < 16; e++) {
        const int c_r = c0 + cb + 4 * hi + (e & 3) + 8 * (e >> 2);
        const float bv = bias[c_r];
#pragma unroll
        for (int ns = 0; ns < 2; ns++) {
            const int rg = n0 + nb + ns * 64 + r;
            const int b = rg >> 11, n = rg & 2047;
            out[((size_t)b * 512 + c_r) * 2048 + n] = acc[ns][e] + bv;
        }
    }
}

// ---------------- workspace layout (bytes) ----------------
static const size_t OFF_XT = 0;
static const size_t OFF_YT = 4194304;
static const size_t OFF_WQT = 8388608;
static const size_t OFF_WKVT = 8912896;
static const size_t OFF_WPT = 9961472;
static const size_t OFF_Q = 10485760;
static const size_t OFF_K = 23068672;
static const size_t OFF_VT = 27262976;
static const size_t OFF_O = 31457280;
static const size_t OFF_PO = 35651584;  // 16 MB bf16 partial O [4][16][2048 n][64 d]
static const size_t OFF_LS = 69206016;  // fp32 partial lsum [4][16][2048]

extern "C" void kernel_launch(void* const* d_in, const int* in_sizes, int n_in,
                              void* d_out, int out_size, void* d_ws, size_t ws_size,
                              hipStream_t stream) {
    const float* x = (const float*)d_in[0];
    const float* y = (const float*)d_in[1];
    const float* Wq = (const float*)d_in[2];
    const float* Wkv = (const float*)d_in[3];
    const float* lw = (const float*)d_in[4];
    const float* lb = (const float*)d_in[5];
    const float* Wp = (const float*)d_in[6];
    const float* bp = (const float*)d_in[7];

    char* ws = (char*)d_ws;
    u16* xT = (u16*)(ws + OFF_XT);
    u16* yT = (u16*)(ws + OFF_YT);
    u16* WqT = (u16*)(ws + OFF_WQT);
    u16* WkvT = (u16*)(ws + OFF_WKVT);
    u16* WpT = (u16*)(ws + OFF_WPT);
    u16* qb = (u16*)(ws + OFF_Q);
    u16* kb = (u16*)(ws + OFF_K);
    u16* vtb = (u16*)(ws + OFF_VT);
    u16* ob = (u16*)(ws + OFF_O);
    u16* po = (u16*)(ws + OFF_PO);
    float* lsw = (float*)(ws + OFF_LS);

    dim3 tb(32, 8, 1);
    transpose_all<<<dim3(64, 16, 5), tb, 0, stream>>>(x, y, Wq, Wkv, Wp, xT, yT, WqT, WkvT,
                                                      WpT);
    proj_qkv<<<dim3(12, 32), 256, 0, stream>>>(xT, yT, WqT, WkvT, lw, lb, qb, kb, vtb);
    flash_attn<<<dim3(512), 256, 0, stream>>>(qb, kb, vtb, po, lsw);
    combine_o<<<dim3(32, 16), 256, 0, stream>>>(po, lsw, ob);
    gemm_out<<<dim3(8, 32), 256, 0, stream>>>(WpT, ob, (float*)d_out, bp);
}